// Round 14
// baseline (307.778 us; speedup 1.0000x reference)
//
#include <hip/hip_runtime.h>
#include <hip/hip_bf16.h>

#define DEVI __device__ __forceinline__

typedef __bf16 bf16x8 __attribute__((ext_vector_type(8)));
typedef float f32x4 __attribute__((ext_vector_type(4)));
typedef unsigned short u16x4 __attribute__((ext_vector_type(4)));
typedef unsigned int u32x2 __attribute__((ext_vector_type(2)));
typedef unsigned long long ull;
typedef int i32x4 __attribute__((ext_vector_type(4)));

constexpr int Nn = 2, Ss = 2048, Ee = 1024, Hh = 16;
constexpr int Ms = Nn * Ss;                       // 4096 rows
constexpr float SCALE = 0.022097086912079608f;    // 1/sqrt(2048) -- key-length scaling!

// workspace layout (bf16 elements)
constexpr size_t SZ_X   = (size_t)Ms * Ee;        // 4,194,304
constexpr size_t EEc    = (size_t)Ee * Ee;
constexpr size_t OFF_QB = 0;                      // Q projected [Ms][Ee]
constexpr size_t OFF_KB = SZ_X;                   // K projected [Ms][Ee]
constexpr size_t OFF_VB = 2 * SZ_X;               // V projected TRANSPOSED [Ee][Ms]
constexpr size_t OFF_XQ = 3 * SZ_X;               // bf16 inputs (3)
constexpr size_t OFF_W  = 6 * SZ_X;               // 4 weights, each Ee*Ee
constexpr size_t OFF_ATTN = OFF_XQ;               // attention out aliases XQ (dead by then)

DEVI unsigned short f2bf(float f) {               // RNE f32->bf16 (no NaN in this data)
  unsigned int u = __builtin_bit_cast(unsigned int, f);
  u += 0x7fffu + ((u >> 16) & 1u);
  return (unsigned short)(u >> 16);
}

DEVI void async16(const void* g, void* l) {
  __builtin_amdgcn_global_load_lds(
      (const __attribute__((address_space(1))) void*)g,
      (__attribute__((address_space(3))) void*)l, 16, 0, 0);
}

DEVI f32x4 mfma_bf16(bf16x8 a, bf16x8 b, f32x4 c) {
  return __builtin_amdgcn_mfma_f32_16x16x32_bf16(a, b, c, 0, 0, 0);
}

DEVI unsigned cvt_pk_bf16(float lo, float hi) {   // v_cvt_pk_bf16_f32: [hi|lo]
  unsigned r;
  asm("v_cvt_pk_bf16_f32 %0, %1, %2" : "=v"(r) : "v"(lo), "v"(hi));
  return r;
}

// ---------------- fp32 -> bf16 convert, all 7 tensors in one launch ----------------
__global__ __launch_bounds__(256) void cvt_all(
    const float* __restrict__ q, const float* __restrict__ k,
    const float* __restrict__ v, const float* __restrict__ wq,
    const float* __restrict__ wk, const float* __restrict__ wv,
    const float* __restrict__ wo, unsigned short* __restrict__ ws)
{
  const int z = blockIdx.z;
  const float* src;
  unsigned short* dst;
  int n4;
  if (z < 3) {
    src = (z == 0) ? q : (z == 1) ? k : v;
    dst = ws + OFF_XQ + (size_t)z * SZ_X;
    n4 = (int)(SZ_X / 4);
  } else {
    const int zz = z - 3;
    src = (zz == 0) ? wq : (zz == 1) ? wk : (zz == 2) ? wv : wo;
    dst = ws + OFF_W + (size_t)zz * EEc;
    n4 = (int)(EEc / 4);
  }
  const int i = blockIdx.x * 256 + threadIdx.x;
  if (i >= n4) return;
  const float4 vv = reinterpret_cast<const float4*>(src)[i];
  u16x4 o = { f2bf(vv.x), f2bf(vv.y), f2bf(vv.z), f2bf(vv.w) };
  reinterpret_cast<u16x4*>(dst)[i] = o;
}

// ---------------- m97 GEMM core: C[bf16] = A @ B^T, K=1024, 128x128 tile -----------
DEVI void gemm_core(const unsigned short* __restrict__ A,
                    const unsigned short* __restrict__ B,
                    unsigned short* __restrict__ C, int ldC,
                    int m0, int n0,
                    unsigned short* As, unsigned short* Bs)
{
  constexpr int K = 1024;
  const int tid = threadIdx.x;
  const int lane = tid & 63, w = tid >> 6;
  const int lr = lane & 15, lg = lane >> 4;
  const int wr = (w >> 1) * 64, wc = (w & 1) * 64;

  const f32x4 zero = {0.f, 0.f, 0.f, 0.f};
  f32x4 acc[4][4];
  for (int a = 0; a < 4; ++a)
    for (int b = 0; b < 4; ++b) acc[a][b] = zero;

  for (int k0 = 0; k0 < K; k0 += 32) {
#pragma unroll
    for (int ii = 0; ii < 2; ++ii) {
      const int i = 2 * w + ii;
      const int boff = i * 1024 + lane * 16;
      const int row = boff >> 6;
      const int colb = boff & 63;
      const char* ga = (const char*)A + ((size_t)(m0 + row) * K + k0) * 2 + colb;
      const char* gb = (const char*)B + ((size_t)(n0 + row) * K + k0) * 2 + colb;
      async16(ga, (char*)As + i * 1024);
      async16(gb, (char*)Bs + i * 1024);
    }
    __syncthreads();

    bf16x8 aF[4], bF[4];
#pragma unroll
    for (int rb = 0; rb < 4; ++rb)
      aF[rb] = *(const bf16x8*)(As + (wr + rb * 16 + lr) * 32 + lg * 8);
#pragma unroll
    for (int cb = 0; cb < 4; ++cb)
      bF[cb] = *(const bf16x8*)(Bs + (wc + cb * 16 + lr) * 32 + lg * 8);
#pragma unroll
    for (int rb = 0; rb < 4; ++rb)
#pragma unroll
      for (int cb = 0; cb < 4; ++cb)
        acc[rb][cb] = mfma_bf16(aF[rb], bF[cb], acc[rb][cb]);
    __syncthreads();
  }

#pragma unroll
  for (int rb = 0; rb < 4; ++rb)
#pragma unroll
    for (int cb = 0; cb < 4; ++cb)
#pragma unroll
      for (int j = 0; j < 4; ++j) {
        const int row = m0 + wr + rb * 16 + lg * 4 + j;   // C/D: col=lane&15
        const int col = n0 + wc + cb * 16 + lr;
        C[(size_t)row * ldC + col] = f2bf(acc[rb][cb][j]);
      }
}

// ---------------- merged QKV projections (one 768-block launch) --------------------
__global__ __launch_bounds__(256) void qkv3(
    const unsigned short* __restrict__ Xq,     // bf16 inputs base (3x)
    const unsigned short* __restrict__ W,      // bf16 weights base (4x)
    unsigned short* __restrict__ QKout,        // Q,K out (2x SZ_X)
    unsigned short* __restrict__ Vtout)        // V^T out [Ee][Ms]
{
  __shared__ unsigned short As[128 * 32];
  __shared__ unsigned short Bs[128 * 32];
  const int b = blockIdx.x;
  if (b < 512) {
    const int z = b >> 8, by = (b >> 3) & 31, bx = b & 7;
    gemm_core(Xq + (size_t)z * SZ_X, W + (size_t)z * EEc,
              QKout + (size_t)z * SZ_X, Ee, by * 128, bx * 128, As, Bs);
  } else {
    const int v = b - 512, bx = v & 31, by = v >> 5;
    gemm_core(W + 2 * EEc, Xq + 2 * SZ_X, Vtout, Ms, by * 128, bx * 128, As, Bs);
  }
}

// ---------------- fused masked attention, 512 q-rows/block -------------------------
// 1024 threads = 16 waves x 32 q-rows; per-wave structure IDENTICAL to the proven
// R13 kernel (256B-granule NT mask loads, nibble LDS table, S^T MFMAs, dbuf K/V,
// raw s_barrier + vmcnt(0)). Halves K/V re-reads again: each nh's K/V is fetched
// by 4 blocks instead of 8 (~128 -> ~64 MB HBM). Staging: threads 0-511 cover the
// K tile, 512-1023 the V tile (one global_load_lds each). Grid 128, 1 block/CU
// (LDS 114.7 KB); BW-bound kernel, so 128 active CUs suffice (per-CU in-flight
// mask bytes 16 waves x 8 KB >> the ~22 KB needed for 50 GB/s/CU).
__global__ __launch_bounds__(1024) void attn_kernel(
    const unsigned short* __restrict__ Qb,
    const unsigned short* __restrict__ Kb,     // [Ms][Ee]
    const unsigned short* __restrict__ Vtb,    // [Ee][Ms]  (pre-transposed)
    const int* __restrict__ mask,
    unsigned short* __restrict__ Ob)
{
  __shared__ unsigned short Kl0[64 * 64], Kl1[64 * 64];
  __shared__ unsigned short Vl0[64 * 64], Vl1[64 * 64];
  __shared__ unsigned short Pw[16 * 32 * 72];    // per-wave P [32 q][144 B rows]
  __shared__ unsigned char Mb[16][32][16];       // per-wave mask nibbles [q][m]

  const int tid = threadIdx.x;
  const int lane = tid & 63, w = tid >> 6;       // w = 0..15
  const int lr = lane & 15, lg = lane >> 4;

  // XCD-locality decode: grid 128; xcd owns 4 nh-groups, 4 q-blocks each
  const int lid = blockIdx.x;
  const int xcd = lid & 7, slot = lid >> 3;      // slot 0..15
  const int g = xcd + 8 * (slot >> 2);           // nh group 0..31
  const int n = g >> 4, h = g & 15;
  const int q0 = (slot & 3) * 512;

  // Q fragments: wave w owns q rows [q0+32w, q0+32w+32)
  bf16x8 aQ[2][2];
#pragma unroll
  for (int qb = 0; qb < 2; ++qb) {
    const unsigned short* qp =
        Qb + ((size_t)(n * Ss + q0 + w * 32 + qb * 16 + lr)) * Ee + h * 64 + lg * 8;
    aQ[qb][0] = *(const bf16x8*)(qp);
    aQ[qb][1] = *(const bf16x8*)(qp + 32);
  }

  // K/V staging: 1024 threads, one 16B chunk each. Threads 0-511 -> K tile,
  // 512-1023 -> V tile. chunk = tid & 511; source pre-swizzled (col16 ^= row&7).
  const int chunk = tid & 511;
  const int row0 = chunk >> 3;
  const int c0 = (chunk & 7) ^ (row0 & 7);
  const int ldsb0 = (chunk >> 6) * 1024;         // wave-uniform LDS byte base
  const bool isK = (w < 8);

  const unsigned short* kp0 = Kb + ((size_t)(n * Ss + row0) * Ee + h * 64 + c0 * 8);
  const unsigned short* vp0 = Vtb + ((size_t)(h * 64 + row0) * Ms + n * Ss + c0 * 8);

  // mask base: instr i covers rows 4i+lg, cols lr*4.. (256B-granule per row)
  const int* mpw = mask + ((size_t)(n * Hh + h) * Ss + (q0 + w * 32 + lg)) * Ss
                        + lr * 4;

  // precomputed swizzled DS byte offsets (per-thread constants)
  int koff[4][2];
#pragma unroll
  for (int cb = 0; cb < 4; ++cb) {
    const int row = cb * 16 + lr;
    koff[cb][0] = row * 128 + ((lg ^ (row & 7)) * 16);
    koff[cb][1] = row * 128 + (((4 + lg) ^ (row & 7)) * 16);
  }
  char* const PwW = (char*)Pw + w * (32 * 144);
  int pwo[2], pro[2];
#pragma unroll
  for (int qb = 0; qb < 2; ++qb) {
    pwo[qb] = (qb * 16 + lr) * 144 + lg * 8;
    pro[qb] = (qb * 16 + lr) * 144 + lg * 16;
  }

  const f32x4 zero = {0.f, 0.f, 0.f, 0.f};
  f32x4 oacc[2][4];
#pragma unroll
  for (int qb = 0; qb < 2; ++qb)
#pragma unroll
    for (int db = 0; db < 4; ++db) oacc[qb][db] = zero;
  float rs[2] = {0.f, 0.f};

  i32x4 pm[8];                                   // mask tile, row-contig 256B chunks
  auto mload = [&]() {
#pragma unroll
    for (int i = 0; i < 8; ++i)
      pm[i] = __builtin_nontemporal_load((const i32x4*)(mpw + (size_t)(4 * i) * Ss));
    mpw += 64;
  };

  // ---- prologue: stage t0 -> buf0; mask t0 -> pm ----
  if (isK) async16(kp0, (char*)Kl0 + ldsb0);
  else     async16(vp0, (char*)Vl0 + ldsb0);
  kp0 += (size_t)64 * Ee; vp0 += 64;
  mload();

  auto tile = [&](const unsigned short* KC, const unsigned short* VC,
                  unsigned short* KN, unsigned short* VN, bool pf) {
    // stage(t) + mask(t) issued a full iteration ago -> landed; sync waves
    asm volatile("s_waitcnt vmcnt(0)" ::: "memory");
    __builtin_amdgcn_s_barrier();

    if (pf) {
      if (isK) async16(kp0, (char*)KN + ldsb0);
      else     async16(vp0, (char*)VN + ldsb0);
      kp0 += (size_t)64 * Ee; vp0 += 64;
    }

    // redistribute mask(t): per-lane nibble pack -> wave-private LDS table
#pragma unroll
    for (int i = 0; i < 8; ++i) {
      const unsigned nib = (pm[i][0] != 0 ? 1u : 0u)
                         | (pm[i][1] != 0 ? 2u : 0u)
                         | (pm[i][2] != 0 ? 4u : 0u)
                         | (pm[i][3] != 0 ? 8u : 0u);
      Mb[w][4 * i + lg][lr] = (unsigned char)nib;   // row 4i+lg, m = lr
    }
    if (pf) mload();                               // refill pm with mask(t+1)

    // S^T = K Q^T per 16-k block; nibble-gated exp; cvt_pk pack; ds_write_b64
#pragma unroll
    for (int cb = 0; cb < 4; ++cb) {
      const bf16x8 kF0 = *(const bf16x8*)((const char*)KC + koff[cb][0]);
      const bf16x8 kF1 = *(const bf16x8*)((const char*)KC + koff[cb][1]);
#pragma unroll
      for (int qb = 0; qb < 2; ++qb) {
        f32x4 a = mfma_bf16(kF0, aQ[qb][0], zero);
        a = mfma_bf16(kF1, aQ[qb][1], a);
        const unsigned nib = Mb[w][qb * 16 + lr][cb * 4 + lg];  // q row, m=cb*4+lg
        float p[4];
#pragma unroll
        for (int j = 0; j < 4; ++j)
          p[j] = ((nib >> j) & 1) ? __expf(a[j] * SCALE) : 0.f;
        rs[qb] += (p[0] + p[1]) + (p[2] + p[3]);
        u32x2 pd = { cvt_pk_bf16(p[0], p[1]), cvt_pk_bf16(p[2], p[3]) };
        *(u32x2*)(PwW + pwo[qb] + cb * 32) = pd;
      }
    }

    // O += P V  (Pw rows wave-private; compiler orders the LDS RAW via lgkmcnt)
    bf16x8 aP[2][2];
#pragma unroll
    for (int qb = 0; qb < 2; ++qb) {
      aP[qb][0] = *(const bf16x8*)(PwW + pro[qb]);
      aP[qb][1] = *(const bf16x8*)(PwW + pro[qb] + 64);
    }
#pragma unroll
    for (int db = 0; db < 4; ++db) {
#pragma unroll
      for (int kc = 0; kc < 2; ++kc) {
        const bf16x8 bV = *(const bf16x8*)((const char*)VC + koff[db][kc]);
#pragma unroll
        for (int qb = 0; qb < 2; ++qb)
          oacc[qb][db] = mfma_bf16(aP[qb][kc], bV, oacc[qb][db]);
      }
    }
  };

  for (int kt2 = 0; kt2 < 16; ++kt2) {
    tile(Kl0, Vl0, Kl1, Vl1, true);
    tile(Kl1, Vl1, Kl0, Vl0, kt2 != 15);
  }

  // rowsum: reduce across the 4 lg groups (q = qb*16+lr), then fetch per-output-q
  float inv[2][4];
#pragma unroll
  for (int qb = 0; qb < 2; ++qb) {
    float r = rs[qb];
    r += __shfl_xor(r, 16, 64);
    r += __shfl_xor(r, 32, 64);
#pragma unroll
    for (int j = 0; j < 4; ++j)
      inv[qb][j] = 1.0f / __shfl(r, lg * 4 + j, 64);
  }
#pragma unroll
  for (int qb = 0; qb < 2; ++qb)
#pragma unroll
    for (int db = 0; db < 4; ++db)
#pragma unroll
      for (int j = 0; j < 4; ++j) {
        const int qr = q0 + w * 32 + qb * 16 + lg * 4 + j;
        Ob[((size_t)(n * Ss + qr)) * Ee + h * 64 + db * 16 + lr] =
            f2bf(oacc[qb][db][j] * inv[qb][j]);
      }
}

// ---------------- output projection + bias -> fp32 --------------------------------
__global__ __launch_bounds__(256) void out_proj(
    const unsigned short* __restrict__ A,      // attn out [Ms][Ee] bf16
    const unsigned short* __restrict__ B,      // Wo [Ee][Ee] bf16
    float* __restrict__ Cf, const float* __restrict__ bias)
{
  __shared__ unsigned short As[128 * 32];
  __shared__ unsigned short Bs[128 * 32];
  constexpr int K = 1024;
  const int tid = threadIdx.x;
  const int lane = tid & 63, w = tid >> 6;
  const int lr = lane & 15, lg = lane >> 4;
  const int m0 = blockIdx.y * 128, n0 = blockIdx.x * 128;
  const int wr = (w >> 1) * 64, wc = (w & 1) * 64;

  const f32x4 zero = {0.f, 0.f, 0.f, 0.f};
  f32x4 acc[4][4];
  for (int a = 0; a < 4; ++a)
    for (int b = 0; b < 4; ++b) acc[a][b] = zero;

  for (int k0 = 0; k0 < K; k0 += 32) {
#pragma unroll
    for (int ii = 0; ii < 2; ++ii) {
      const int i = 2 * w + ii;
      const int boff = i * 1024 + lane * 16;
      const int row = boff >> 6;
      const int colb = boff & 63;
      const char* ga = (const char*)A + ((size_t)(m0 + row) * K + k0) * 2 + colb;
      const char* gb = (const char*)B + ((size_t)(n0 + row) * K + k0) * 2 + colb;
      async16(ga, (char*)As + i * 1024);
      async16(gb, (char*)Bs + i * 1024);
    }
    __syncthreads();

    bf16x8 aF[4], bF[4];
#pragma unroll
    for (int rb = 0; rb < 4; ++rb)
      aF[rb] = *(const bf16x8*)(As + (wr + rb * 16 + lr) * 32 + lg * 8);
#pragma unroll
    for (int cb = 0; cb < 4; ++cb)
      bF[cb] = *(const bf16x8*)(Bs + (wc + cb * 16 + lr) * 32 + lg * 8);
#pragma unroll
    for (int rb = 0; rb < 4; ++rb)
#pragma unroll
      for (int cb = 0; cb < 4; ++cb)
        acc[rb][cb] = mfma_bf16(aF[rb], bF[cb], acc[rb][cb]);
    __syncthreads();
  }

#pragma unroll
  for (int rb = 0; rb < 4; ++rb)
#pragma unroll
    for (int cb = 0; cb < 4; ++cb)
#pragma unroll
      for (int j = 0; j < 4; ++j) {
        const int row = m0 + wr + rb * 16 + lg * 4 + j;
        const int col = n0 + wc + cb * 16 + lr;
        Cf[(size_t)row * Ee + col] = acc[rb][cb][j] + bias[col];
      }
}

// -----------------------------------------------------------------------------------
extern "C" void kernel_launch(void* const* d_in, const int* in_sizes, int n_in,
                              void* d_out, int out_size, void* d_ws, size_t ws_size,
                              hipStream_t stream) {
  const float* qin = (const float*)d_in[0];
  const float* kin = (const float*)d_in[1];
  const float* vin = (const float*)d_in[2];
  const int*   msk = (const int*)d_in[3];
  const float* Wq  = (const float*)d_in[4];
  const float* Wk  = (const float*)d_in[5];
  const float* Wv  = (const float*)d_in[6];
  const float* Wo  = (const float*)d_in[7];
  const float* bo  = (const float*)d_in[8];
  unsigned short* ws = (unsigned short*)d_ws;

  // 1) convert inputs + weights to bf16 (single launch, 7 z-slices)
  cvt_all<<<dim3((unsigned)(SZ_X / 4 / 256), 1, 7), 256, 0, stream>>>(
      qin, kin, vin, Wq, Wk, Wv, Wo, ws);

  // 2) Q/K projections + V^T projection (single 768-block launch)
  qkv3<<<dim3(768), 256, 0, stream>>>(
      ws + OFF_XQ, ws + OFF_W, ws + OFF_QB, ws + OFF_VB);

  // 3) masked attention (grid 128, 1024 threads, 512 q-rows/block)
  attn_kernel<<<dim3(128), 1024, 0, stream>>>(
      ws + OFF_QB, ws + OFF_KB, ws + OFF_VB, msk, ws + OFF_ATTN);

  // 4) output projection + bias -> fp32 d_out
  out_proj<<<dim3(8, 32), 256, 0, stream>>>(
      ws + OFF_ATTN, ws + OFF_W + 3 * EEc, (float*)d_out, bo);
}

// Round 15
// 213.915 us; speedup vs baseline: 1.4388x; 1.4388x over previous
//
#include <hip/hip_runtime.h>
#include <hip/hip_bf16.h>

#define DEVI __device__ __forceinline__

typedef __bf16 bf16x8 __attribute__((ext_vector_type(8)));
typedef float f32x4 __attribute__((ext_vector_type(4)));
typedef unsigned short u16x4 __attribute__((ext_vector_type(4)));
typedef unsigned int u32x2 __attribute__((ext_vector_type(2)));
typedef unsigned long long ull;
typedef int i32x4 __attribute__((ext_vector_type(4)));

constexpr int Nn = 2, Ss = 2048, Ee = 1024, Hh = 16;
constexpr int Ms = Nn * Ss;                       // 4096 rows
constexpr float SCALE = 0.022097086912079608f;    // 1/sqrt(2048) -- key-length scaling!

// workspace layout (bf16 elements)
constexpr size_t SZ_X   = (size_t)Ms * Ee;        // 4,194,304
constexpr size_t EEc    = (size_t)Ee * Ee;
constexpr size_t OFF_QB = 0;                      // Q projected [Ms][Ee]
constexpr size_t OFF_KB = SZ_X;                   // K projected [Ms][Ee]
constexpr size_t OFF_VB = 2 * SZ_X;               // V projected TRANSPOSED [Ee][Ms]
constexpr size_t OFF_XQ = 3 * SZ_X;               // bf16 inputs (3)
constexpr size_t OFF_W  = 6 * SZ_X;               // 4 weights, each Ee*Ee
constexpr size_t OFF_ATTN = OFF_XQ;               // attention out aliases XQ (dead by then)

DEVI unsigned short f2bf(float f) {               // RNE f32->bf16 (no NaN in this data)
  unsigned int u = __builtin_bit_cast(unsigned int, f);
  u += 0x7fffu + ((u >> 16) & 1u);
  return (unsigned short)(u >> 16);
}

DEVI void async16(const void* g, void* l) {
  __builtin_amdgcn_global_load_lds(
      (const __attribute__((address_space(1))) void*)g,
      (__attribute__((address_space(3))) void*)l, 16, 0, 0);
}

DEVI f32x4 mfma_bf16(bf16x8 a, bf16x8 b, f32x4 c) {
  return __builtin_amdgcn_mfma_f32_16x16x32_bf16(a, b, c, 0, 0, 0);
}

DEVI unsigned cvt_pk_bf16(float lo, float hi) {   // v_cvt_pk_bf16_f32: [hi|lo]
  unsigned r;
  asm("v_cvt_pk_bf16_f32 %0, %1, %2" : "=v"(r) : "v"(lo), "v"(hi));
  return r;
}

// ---------------- fp32 -> bf16 convert, flat 1D grid (no no-op blocks) -------------
__global__ __launch_bounds__(256) void cvt_all(
    const float* __restrict__ q, const float* __restrict__ k,
    const float* __restrict__ v, const float* __restrict__ wq,
    const float* __restrict__ wk, const float* __restrict__ wv,
    const float* __restrict__ wo, unsigned short* __restrict__ ws)
{
  constexpr size_t Q4 = SZ_X / 4;                 // 1,048,576 float4 per input
  constexpr size_t W4 = EEc / 4;                  // 262,144 float4 per weight
  constexpr size_t NX = 3 * Q4;                   // inputs region
  const size_t i = (size_t)blockIdx.x * 256 + threadIdx.x;
  const float* src;
  unsigned short* dst;
  size_t off;
  if (i < NX) {
    const int z = (int)(i / Q4);
    off = i - (size_t)z * Q4;
    src = (z == 0) ? q : (z == 1) ? k : v;
    dst = ws + OFF_XQ + (size_t)z * SZ_X;
  } else {
    const size_t j = i - NX;
    const int zz = (int)(j / W4);
    off = j - (size_t)zz * W4;
    src = (zz == 0) ? wq : (zz == 1) ? wk : (zz == 2) ? wv : wo;
    dst = ws + OFF_W + (size_t)zz * EEc;
  }
  const float4 vv = reinterpret_cast<const float4*>(src)[off];
  u16x4 o = { f2bf(vv.x), f2bf(vv.y), f2bf(vv.z), f2bf(vv.w) };
  reinterpret_cast<u16x4*>(dst)[off] = o;
}

// ---------------- m97 GEMM core: C[bf16] = A @ B^T, K=1024, 128x128 tile -----------
DEVI void gemm_core(const unsigned short* __restrict__ A,
                    const unsigned short* __restrict__ B,
                    unsigned short* __restrict__ C, int ldC,
                    int m0, int n0,
                    unsigned short* As, unsigned short* Bs)
{
  constexpr int K = 1024;
  const int tid = threadIdx.x;
  const int lane = tid & 63, w = tid >> 6;
  const int lr = lane & 15, lg = lane >> 4;
  const int wr = (w >> 1) * 64, wc = (w & 1) * 64;

  const f32x4 zero = {0.f, 0.f, 0.f, 0.f};
  f32x4 acc[4][4];
  for (int a = 0; a < 4; ++a)
    for (int b = 0; b < 4; ++b) acc[a][b] = zero;

  for (int k0 = 0; k0 < K; k0 += 32) {
#pragma unroll
    for (int ii = 0; ii < 2; ++ii) {
      const int i = 2 * w + ii;
      const int boff = i * 1024 + lane * 16;
      const int row = boff >> 6;
      const int colb = boff & 63;
      const char* ga = (const char*)A + ((size_t)(m0 + row) * K + k0) * 2 + colb;
      const char* gb = (const char*)B + ((size_t)(n0 + row) * K + k0) * 2 + colb;
      async16(ga, (char*)As + i * 1024);
      async16(gb, (char*)Bs + i * 1024);
    }
    __syncthreads();

    bf16x8 aF[4], bF[4];
#pragma unroll
    for (int rb = 0; rb < 4; ++rb)
      aF[rb] = *(const bf16x8*)(As + (wr + rb * 16 + lr) * 32 + lg * 8);
#pragma unroll
    for (int cb = 0; cb < 4; ++cb)
      bF[cb] = *(const bf16x8*)(Bs + (wc + cb * 16 + lr) * 32 + lg * 8);
#pragma unroll
    for (int rb = 0; rb < 4; ++rb)
#pragma unroll
      for (int cb = 0; cb < 4; ++cb)
        acc[rb][cb] = mfma_bf16(aF[rb], bF[cb], acc[rb][cb]);
    __syncthreads();
  }

#pragma unroll
  for (int rb = 0; rb < 4; ++rb)
#pragma unroll
    for (int cb = 0; cb < 4; ++cb)
#pragma unroll
      for (int j = 0; j < 4; ++j) {
        const int row = m0 + wr + rb * 16 + lg * 4 + j;   // C/D: col=lane&15
        const int col = n0 + wc + cb * 16 + lr;
        C[(size_t)row * ldC + col] = f2bf(acc[rb][cb][j]);
      }
}

// ---------------- merged QKV projections (one 768-block launch) --------------------
__global__ __launch_bounds__(256) void qkv3(
    const unsigned short* __restrict__ Xq,     // bf16 inputs base (3x)
    const unsigned short* __restrict__ W,      // bf16 weights base (4x)
    unsigned short* __restrict__ QKout,        // Q,K out (2x SZ_X)
    unsigned short* __restrict__ Vtout)        // V^T out [Ee][Ms]
{
  __shared__ unsigned short As[128 * 32];
  __shared__ unsigned short Bs[128 * 32];
  const int b = blockIdx.x;
  if (b < 512) {
    const int z = b >> 8, by = (b >> 3) & 31, bx = b & 7;
    gemm_core(Xq + (size_t)z * SZ_X, W + (size_t)z * EEc,
              QKout + (size_t)z * SZ_X, Ee, by * 128, bx * 128, As, Bs);
  } else {
    const int v = b - 512, bx = v & 31, by = v >> 5;
    gemm_core(W + 2 * EEc, Xq + 2 * SZ_X, Vtout, Ms, by * 128, bx * 128, As, Bs);
  }
}

// ---------------- fused masked attention, 256 q-rows/block (R13 proven) ------------
// 512 threads = 8 waves x 32 q-rows. 256B-granule NT mask loads (R12 win), nibble
// redistribution via wave-private LDS table, dbuf K/V via global_load_lds with
// pre-swizzled source, raw s_barrier + vmcnt(0) at tile top. Grid 256 -- R14
// proved >=256 blocks spread over all CUs is required to saturate HBM.
__global__ __launch_bounds__(512) void attn_kernel(
    const unsigned short* __restrict__ Qb,
    const unsigned short* __restrict__ Kb,     // [Ms][Ee]
    const unsigned short* __restrict__ Vtb,    // [Ee][Ms]  (pre-transposed)
    const int* __restrict__ mask,
    unsigned short* __restrict__ Ob)
{
  __shared__ unsigned short Kl0[64 * 64], Kl1[64 * 64];
  __shared__ unsigned short Vl0[64 * 64], Vl1[64 * 64];
  __shared__ unsigned short Pw[8 * 32 * 72];     // per-wave P [32 q][144 B rows]
  __shared__ unsigned char Mb[8][32][16];        // per-wave mask nibbles [q][m]

  const int tid = threadIdx.x;
  const int lane = tid & 63, w = tid >> 6;       // w = 0..7
  const int lr = lane & 15, lg = lane >> 4;

  // XCD-locality decode: grid 256; xcd owns 4 nh-groups, 8 q-blocks each
  const int lid = blockIdx.x;
  const int xcd = lid & 7, slot = lid >> 3;      // slot 0..31
  const int g = xcd + 8 * (slot >> 3);           // nh group 0..31
  const int n = g >> 4, h = g & 15;
  const int q0 = (slot & 7) * 256;

  // Q fragments: wave w owns q rows [q0+32w, q0+32w+32)
  bf16x8 aQ[2][2];
#pragma unroll
  for (int qb = 0; qb < 2; ++qb) {
    const unsigned short* qp =
        Qb + ((size_t)(n * Ss + q0 + w * 32 + qb * 16 + lr)) * Ee + h * 64 + lg * 8;
    aQ[qb][0] = *(const bf16x8*)(qp);
    aQ[qb][1] = *(const bf16x8*)(qp + 32);
  }

  // K/V staging: 512 threads x 1 chunk per buffer (16B each), source pre-swizzled
  const int sig0 = w * 64 + lane;                // 0..511 chunk of 8KB tile
  const int row0 = sig0 >> 3;
  const int c0 = (sig0 & 7) ^ (row0 & 7);
  const int ldsb0 = w * 1024;                    // wave-uniform LDS byte base

  const unsigned short* kp0 = Kb + ((size_t)(n * Ss + row0) * Ee + h * 64 + c0 * 8);
  const unsigned short* vp0 = Vtb + ((size_t)(h * 64 + row0) * Ms + n * Ss + c0 * 8);

  // mask base: instr i covers rows 4i+lg, cols lr*4.. (256B-granule per row)
  const int* mpw = mask + ((size_t)(n * Hh + h) * Ss + (q0 + w * 32 + lg)) * Ss
                        + lr * 4;

  // precomputed swizzled DS byte offsets (per-thread constants)
  int koff[4][2];
#pragma unroll
  for (int cb = 0; cb < 4; ++cb) {
    const int row = cb * 16 + lr;
    koff[cb][0] = row * 128 + ((lg ^ (row & 7)) * 16);
    koff[cb][1] = row * 128 + (((4 + lg) ^ (row & 7)) * 16);
  }
  char* const PwW = (char*)Pw + w * (32 * 144);
  int pwo[2], pro[2];
#pragma unroll
  for (int qb = 0; qb < 2; ++qb) {
    pwo[qb] = (qb * 16 + lr) * 144 + lg * 8;
    pro[qb] = (qb * 16 + lr) * 144 + lg * 16;
  }

  const f32x4 zero = {0.f, 0.f, 0.f, 0.f};
  f32x4 oacc[2][4];
#pragma unroll
  for (int qb = 0; qb < 2; ++qb)
#pragma unroll
    for (int db = 0; db < 4; ++db) oacc[qb][db] = zero;
  float rs[2] = {0.f, 0.f};

  i32x4 pm[8];                                   // mask tile, row-contig 256B chunks
  auto mload = [&]() {
#pragma unroll
    for (int i = 0; i < 8; ++i)
      pm[i] = __builtin_nontemporal_load((const i32x4*)(mpw + (size_t)(4 * i) * Ss));
    mpw += 64;
  };

  // ---- prologue: stage t0 -> buf0; mask t0 -> pm ----
  async16(kp0, (char*)Kl0 + ldsb0);
  async16(vp0, (char*)Vl0 + ldsb0);
  kp0 += (size_t)64 * Ee; vp0 += 64;
  mload();

  auto tile = [&](const unsigned short* KC, const unsigned short* VC,
                  unsigned short* KN, unsigned short* VN, bool pf) {
    // stage(t) + mask(t) issued a full iteration ago -> landed; sync waves
    asm volatile("s_waitcnt vmcnt(0)" ::: "memory");
    __builtin_amdgcn_s_barrier();

    if (pf) {
      async16(kp0, (char*)KN + ldsb0);
      async16(vp0, (char*)VN + ldsb0);
      kp0 += (size_t)64 * Ee; vp0 += 64;
    }

    // redistribute mask(t): per-lane nibble pack -> wave-private LDS table
#pragma unroll
    for (int i = 0; i < 8; ++i) {
      const unsigned nib = (pm[i][0] != 0 ? 1u : 0u)
                         | (pm[i][1] != 0 ? 2u : 0u)
                         | (pm[i][2] != 0 ? 4u : 0u)
                         | (pm[i][3] != 0 ? 8u : 0u);
      Mb[w][4 * i + lg][lr] = (unsigned char)nib;   // row 4i+lg, m = lr
    }
    if (pf) mload();                               // refill pm with mask(t+1)

    // S^T = K Q^T per 16-k block; nibble-gated exp; cvt_pk pack; ds_write_b64
#pragma unroll
    for (int cb = 0; cb < 4; ++cb) {
      const bf16x8 kF0 = *(const bf16x8*)((const char*)KC + koff[cb][0]);
      const bf16x8 kF1 = *(const bf16x8*)((const char*)KC + koff[cb][1]);
#pragma unroll
      for (int qb = 0; qb < 2; ++qb) {
        f32x4 a = mfma_bf16(kF0, aQ[qb][0], zero);
        a = mfma_bf16(kF1, aQ[qb][1], a);
        const unsigned nib = Mb[w][qb * 16 + lr][cb * 4 + lg];  // q row, m=cb*4+lg
        float p[4];
#pragma unroll
        for (int j = 0; j < 4; ++j)
          p[j] = ((nib >> j) & 1) ? __expf(a[j] * SCALE) : 0.f;
        rs[qb] += (p[0] + p[1]) + (p[2] + p[3]);
        u32x2 pd = { cvt_pk_bf16(p[0], p[1]), cvt_pk_bf16(p[2], p[3]) };
        *(u32x2*)(PwW + pwo[qb] + cb * 32) = pd;
      }
    }

    // O += P V  (Pw rows wave-private; compiler orders the LDS RAW via lgkmcnt)
    bf16x8 aP[2][2];
#pragma unroll
    for (int qb = 0; qb < 2; ++qb) {
      aP[qb][0] = *(const bf16x8*)(PwW + pro[qb]);
      aP[qb][1] = *(const bf16x8*)(PwW + pro[qb] + 64);
    }
#pragma unroll
    for (int db = 0; db < 4; ++db) {
#pragma unroll
      for (int kc = 0; kc < 2; ++kc) {
        const bf16x8 bV = *(const bf16x8*)((const char*)VC + koff[db][kc]);
#pragma unroll
        for (int qb = 0; qb < 2; ++qb)
          oacc[qb][db] = mfma_bf16(aP[qb][kc], bV, oacc[qb][db]);
      }
    }
  };

  for (int kt2 = 0; kt2 < 16; ++kt2) {
    tile(Kl0, Vl0, Kl1, Vl1, true);
    tile(Kl1, Vl1, Kl0, Vl0, kt2 != 15);
  }

  // rowsum: reduce across the 4 lg groups (q = qb*16+lr), then fetch per-output-q
  float inv[2][4];
#pragma unroll
  for (int qb = 0; qb < 2; ++qb) {
    float r = rs[qb];
    r += __shfl_xor(r, 16, 64);
    r += __shfl_xor(r, 32, 64);
#pragma unroll
    for (int j = 0; j < 4; ++j)
      inv[qb][j] = 1.0f / __shfl(r, lg * 4 + j, 64);
  }
#pragma unroll
  for (int qb = 0; qb < 2; ++qb)
#pragma unroll
    for (int db = 0; db < 4; ++db)
#pragma unroll
      for (int j = 0; j < 4; ++j) {
        const int qr = q0 + w * 32 + qb * 16 + lg * 4 + j;
        Ob[((size_t)(n * Ss + qr)) * Ee + h * 64 + db * 16 + lr] =
            f2bf(oacc[qb][db][j] * inv[qb][j]);
      }
}

// ---------------- output projection + bias -> fp32 --------------------------------
__global__ __launch_bounds__(256) void out_proj(
    const unsigned short* __restrict__ A,      // attn out [Ms][Ee] bf16
    const unsigned short* __restrict__ B,      // Wo [Ee][Ee] bf16
    float* __restrict__ Cf, const float* __restrict__ bias)
{
  __shared__ unsigned short As[128 * 32];
  __shared__ unsigned short Bs[128 * 32];
  constexpr int K = 1024;
  const int tid = threadIdx.x;
  const int lane = tid & 63, w = tid >> 6;
  const int lr = lane & 15, lg = lane >> 4;
  const int m0 = blockIdx.y * 128, n0 = blockIdx.x * 128;
  const int wr = (w >> 1) * 64, wc = (w & 1) * 64;

  const f32x4 zero = {0.f, 0.f, 0.f, 0.f};
  f32x4 acc[4][4];
  for (int a = 0; a < 4; ++a)
    for (int b = 0; b < 4; ++b) acc[a][b] = zero;

  for (int k0 = 0; k0 < K; k0 += 32) {
#pragma unroll
    for (int ii = 0; ii < 2; ++ii) {
      const int i = 2 * w + ii;
      const int boff = i * 1024 + lane * 16;
      const int row = boff >> 6;
      const int colb = boff & 63;
      const char* ga = (const char*)A + ((size_t)(m0 + row) * K + k0) * 2 + colb;
      const char* gb = (const char*)B + ((size_t)(n0 + row) * K + k0) * 2 + colb;
      async16(ga, (char*)As + i * 1024);
      async16(gb, (char*)Bs + i * 1024);
    }
    __syncthreads();

    bf16x8 aF[4], bF[4];
#pragma unroll
    for (int rb = 0; rb < 4; ++rb)
      aF[rb] = *(const bf16x8*)(As + (wr + rb * 16 + lr) * 32 + lg * 8);
#pragma unroll
    for (int cb = 0; cb < 4; ++cb)
      bF[cb] = *(const bf16x8*)(Bs + (wc + cb * 16 + lr) * 32 + lg * 8);
#pragma unroll
    for (int rb = 0; rb < 4; ++rb)
#pragma unroll
      for (int cb = 0; cb < 4; ++cb)
        acc[rb][cb] = mfma_bf16(aF[rb], bF[cb], acc[rb][cb]);
    __syncthreads();
  }

#pragma unroll
  for (int rb = 0; rb < 4; ++rb)
#pragma unroll
    for (int cb = 0; cb < 4; ++cb)
#pragma unroll
      for (int j = 0; j < 4; ++j) {
        const int row = m0 + wr + rb * 16 + lg * 4 + j;
        const int col = n0 + wc + cb * 16 + lr;
        Cf[(size_t)row * Ee + col] = acc[rb][cb][j] + bias[col];
      }
}

// -----------------------------------------------------------------------------------
extern "C" void kernel_launch(void* const* d_in, const int* in_sizes, int n_in,
                              void* d_out, int out_size, void* d_ws, size_t ws_size,
                              hipStream_t stream) {
  const float* qin = (const float*)d_in[0];
  const float* kin = (const float*)d_in[1];
  const float* vin = (const float*)d_in[2];
  const int*   msk = (const int*)d_in[3];
  const float* Wq  = (const float*)d_in[4];
  const float* Wk  = (const float*)d_in[5];
  const float* Wv  = (const float*)d_in[6];
  const float* Wo  = (const float*)d_in[7];
  const float* bo  = (const float*)d_in[8];
  unsigned short* ws = (unsigned short*)d_ws;

  // 1) convert inputs + weights to bf16 (flat 1D grid, exactly 16384 blocks)
  cvt_all<<<dim3(16384), 256, 0, stream>>>(
      qin, kin, vin, Wq, Wk, Wv, Wo, ws);

  // 2) Q/K projections + V^T projection (single 768-block launch)
  qkv3<<<dim3(768), 256, 0, stream>>>(
      ws + OFF_XQ, ws + OFF_W, ws + OFF_QB, ws + OFF_VB);

  // 3) masked attention (grid 256, 512 threads, 256 q-rows/block -- R13 proven)
  attn_kernel<<<dim3(256), 512, 0, stream>>>(
      ws + OFF_QB, ws + OFF_KB, ws + OFF_VB, msk, ws + OFF_ATTN);

  // 4) output projection + bias -> fp32 d_out
  out_proj<<<dim3(8, 32), 256, 0, stream>>>(
      ws + OFF_ATTN, ws + OFF_W + 3 * EEc, (float*)d_out, bo);
}